// Round 4
// baseline (88.440 us; speedup 1.0000x reference)
//
#include <hip/hip_runtime.h>
#include <hip/hip_bf16.h>

// 3x3 VALID conv via bf16 MFMA implicit GEMM.
// x: (64,224,224) fp32, w: (128,64,3,3) fp32, out: (128,222,222) fp32.
//
// R13: two launches, NO x-transpose kernel. Evidence: R9/R11/R12 (three
// structurally different pipelines) all measure 88.0-88.6us; R10 isolated a
// ~76us fixed harness cost (43.5us 256MiB ws poison-fill + ~32us reset
// dispatches), so our kernels total ~12us and only that part is controllable.
// The transpose kernel existed solely to hand conv a c-contiguous layout;
// conv now builds xs[row][wc][c] directly from fp32 x while staging:
//   item = (row, wc, c-octet): 8 strided scalar loads (coalesced across lanes,
//   wc fastest), fp32->bf16, one 16B ds_write. Write stride 144B = 36 dwords
//   -> lanes 0..7 cover all 32 banks once -> conflict-free (same pattern as
//   the verified B-read). Zero-fill at h/w edges (OOB only feeds masked
//   outputs). Saves: transpose kernel (~3us) + launch gap (~1.5us) + 6.5MB
//   xt round-trip (~1us); adds ~0.5-1us staging work.
// MFMA loop/epilogue = R12 verbatim (barrier-free, A-from-global, mi2 x ni2).
// A: m=lane&31, k=(lane>>5)*8+j. B: n=lane&31. D: col=lane&31,
// row=(reg&3)+8*(reg>>2)+4*(lane>>5)  [m74/m101-verified].

#define H_IN   224
#define W_IN   224
#define C_OUT  128
#define H_OUT  222
#define W_OUT  222
#define CPAD   72    // padded c stride in conv x-LDS (144B = 16B*9, bank-floor)

typedef __attribute__((ext_vector_type(8)))  short bf16x8;
typedef __attribute__((ext_vector_type(16))) float f32x16;

static __device__ __forceinline__ unsigned short f2bs(float f) {
    union { __hip_bfloat16 h; unsigned short u; } cv;
    cv.h = __float2bfloat16(f);
    return cv.u;
}

// wt layout: [ij][kstep(=c>>3)][co][c&7] -> A-fragment reads lane-contiguous.
__global__ __launch_bounds__(256)
void transform_w_kernel(const float* __restrict__ w, __hip_bfloat16* __restrict__ wt)
{
    int idx = blockIdx.x * 256 + threadIdx.x;     // 9*128*64 = 73,728
    if (idx < 9 * 128 * 64) {
        int ij  = idx >> 13;
        int rem = idx & 8191;
        int co  = rem >> 6;
        int c   = rem & 63;
        wt[((ij * 8 + (c >> 3)) * 128 + co) * 8 + (c & 7)] =
            __float2bfloat16(w[(co * 64 + c) * 9 + ij]);
    }
}

__global__ __launch_bounds__(128, 2)
void conv_mfma_kernel(const float* __restrict__ x,
                      const __hip_bfloat16* __restrict__ wt,
                      float* __restrict__ out)
{
    __shared__ __hip_bfloat16 xs[6 * 34 * CPAD];   // [row][wc][c]  29,376 B
    const int ow0 = blockIdx.x * 32;
    const int oh0 = blockIdx.y * 4;
    const int co0 = blockIdx.z * 64;
    const int tid = threadIdx.x;

    // Stage xs[row][wc][c] (bf16) directly from x (fp32 CHW).
    // q = (row*8 + sub)*34 + wc, wc fastest across lanes -> coalesced 136B
    // runs per scalar load; 8 c-strided loads pack into one 16B LDS write.
    for (int q = tid; q < 6 * 8 * 34; q += 128) {
        const int wc  = q % 34;
        const int rs  = q / 34;
        const int row = rs >> 3;
        const int sub = rs & 7;
        const int hh  = oh0 + row;          // input row, may exceed 223 at edge
        const int ww  = ow0 + wc;           // input col, may exceed 223 at edge
        alignas(16) unsigned short r[8];
        if (hh < H_IN && ww < W_IN) {
            const float* src = x + ((size_t)(sub * 8) * H_IN + hh) * W_IN + ww;
            #pragma unroll
            for (int j = 0; j < 8; ++j)
                r[j] = f2bs(src[(size_t)j * H_IN * W_IN]);
        } else {
            #pragma unroll
            for (int j = 0; j < 8; ++j) r[j] = 0;   // zero-pad: only feeds masked outputs
        }
        *(float4*)(xs + (row * 34 + wc) * CPAD + sub * 8) = *(const float4*)r;
    }
    __syncthreads();   // the ONLY barrier: xs is read-only from here on

    const int wave = tid >> 6;      // 0..1
    const int lane = tid & 63;
    const int n    = lane & 31;     // A: co offset; B: ow offset; D: col
    const int h    = lane >> 5;     // k-half selector
    const int r0   = wave * 2;      // this wave's 2 output rows

    f32x16 acc[2][2] = {};          // [mi][ni]

    #pragma unroll
    for (int p = 0; p < 9; ++p) {   // tap index = i*3 + jj
        const int i  = p / 3;
        const int jj = p - i * 3;
        #pragma unroll
        for (int t = 0; t < 4; ++t) {
            // A-fragments straight from global (L1/L2-resident, 1KB/wave
            // coalesced); each feeds 2 MFMAs via the ni=2 tile.
            bf16x8 afr[2], bfr[2];
            #pragma unroll
            for (int mi = 0; mi < 2; ++mi)
                afr[mi] = *(const bf16x8*)(wt +
                    (size_t)(((p * 8 + t * 2 + h) * 128 + co0 + mi * 32 + n) * 8));
            #pragma unroll
            for (int ni = 0; ni < 2; ++ni)
                bfr[ni] = *(const bf16x8*)(xs +
                    ((i + r0 + ni) * 34 + n + jj) * CPAD + t * 16 + h * 8);
            #pragma unroll
            for (int mi = 0; mi < 2; ++mi)
                #pragma unroll
                for (int ni = 0; ni < 2; ++ni)
                    acc[mi][ni] = __builtin_amdgcn_mfma_f32_32x32x16_bf16(
                        afr[mi], bfr[ni], acc[mi][ni], 0, 0, 0);
        }
    }

    // Epilogue: lanes 0..31 = 32 consecutive ow -> 128B full-line stores.
    #pragma unroll
    for (int mi = 0; mi < 2; ++mi) {
        #pragma unroll
        for (int ni = 0; ni < 2; ++ni) {
            const int oh = oh0 + r0 + ni;
            const int ow = ow0 + n;
            if (oh < H_OUT && ow < W_OUT) {
                #pragma unroll
                for (int r = 0; r < 16; ++r) {
                    int co = co0 + mi * 32 + (r & 3) + 8 * (r >> 2) + 4 * h;
                    out[(size_t)co * (H_OUT * W_OUT) + oh * W_OUT + ow] = acc[mi][ni][r];
                }
            }
        }
    }
}

extern "C" void kernel_launch(void* const* d_in, const int* in_sizes, int n_in,
                              void* d_out, int out_size, void* d_ws, size_t ws_size,
                              hipStream_t stream)
{
    const float* x = (const float*)d_in[0];
    const float* w = (const float*)d_in[1];
    float* out     = (float*)d_out;

    __hip_bfloat16* wt = (__hip_bfloat16*)d_ws;    // 9*128*64*2 = 147,456 B

    transform_w_kernel<<<288, 256, 0, stream>>>(w, wt);
    conv_mfma_kernel<<<dim3(7, 56, 2), 128, 0, stream>>>(x, wt, out);
}